// Round 4
// baseline (1436.709 us; speedup 1.0000x reference)
//
#include <hip/hip_runtime.h>
#include <hip/hip_bf16.h>
#include <cstdint>
#include <cstddef>

typedef __bf16 bf16_t;
typedef __bf16 bf16x8 __attribute__((ext_vector_type(8)));
typedef __bf16 bf16x4 __attribute__((ext_vector_type(4)));
typedef float f32x4 __attribute__((ext_vector_type(4)));

static constexpr int LD = 29 * 128;  // 3712 floats per row of x / out

// ---------------- prep kernels ----------------

__global__ void cvt_w0_pad_kernel(const float* __restrict__ in, bf16_t* __restrict__ out,
                                  int rows_real, int kdim, int total) {
    int idx = blockIdx.x * 256 + threadIdx.x;
    if (idx >= total) return;
    int r = idx / kdim;
    int c = idx - r * kdim;
    out[idx] = (bf16_t)((r < rows_real) ? in[(size_t)r * kdim + c] : 0.f);
}

// Wc (2*of x 2*din) from W (2*of x din):
//   rows [0,of):    Wc[j]      = [ W[j,:],    -W[j+of,:] ]
//   rows [of,2of):  Wc[of + j] = [ W[j+of,:],  W[j,:]    ]
__global__ void combine_wm_kernel(const float* __restrict__ W, bf16_t* __restrict__ Wc,
                                  int of, int din, int total) {
    int idx = blockIdx.x * 256 + threadIdx.x;
    if (idx >= total) return;
    int twodin = 2 * din;
    int r = idx / twodin;
    int c = idx - r * twodin;
    float v;
    if (r < of) {
        v = (c < din) ? W[(size_t)r * din + c]
                      : -W[(size_t)(r + of) * din + (c - din)];
    } else {
        int j = r - of;
        v = (c < din) ? W[(size_t)(j + of) * din + c]
                      : W[(size_t)j * din + (c - din)];
    }
    Wc[idx] = (bf16_t)v;
}

__global__ void cvt_x_kernel(const float* __restrict__ in, bf16_t* __restrict__ out, long n8) {
    long stride = (long)gridDim.x * 256;
    for (long i = blockIdx.x * 256L + threadIdx.x; i < n8; i += stride) {
        f32x4 v0 = *(const f32x4*)(in + i * 8);
        f32x4 v1 = *(const f32x4*)(in + i * 8 + 4);
        bf16x8 h;
        h[0] = (bf16_t)v0[0]; h[1] = (bf16_t)v0[1];
        h[2] = (bf16_t)v0[2]; h[3] = (bf16_t)v0[3];
        h[4] = (bf16_t)v1[0]; h[5] = (bf16_t)v1[1];
        h[6] = (bf16_t)v1[2]; h[7] = (bf16_t)v1[3];
        *(bf16x8*)(out + i * 8) = h;
    }
}

// ---------------- persistent fused 8-phase GEMM ----------------
// 15*mt tiles: seg0 (N=1024pad,K=896,4 cols), seg1 (1536,24kt,6), seg2 (1280,20kt,5).
// 256 blocks x 512 thr walk tiles t = bid + i*gridDim. Stage-ahead crosses tile
// boundaries: never drains vmcnt mid-stream.

struct TileDesc {
    const bf16_t* A;    // xb + xoff  (row stride LD)
    const bf16_t* W;    // wseg + n0*K (row stride K)
    float* Y;           // out + outoff + n0
    const float* bias;  // b0 + n0 or nullptr
    long m0;
    int K;
    int NT;
    int ncol;           // valid cols in this 256-tile
};

#define MMA_Q(QM, QN, AF)                                                            \
    do {                                                                             \
        __builtin_amdgcn_s_setprio(1);                                               \
        _Pragma("unroll") for (int i_ = 0; i_ < 2; ++i_)                             \
        _Pragma("unroll") for (int j_ = 0; j_ < 4; ++j_)                             \
        _Pragma("unroll") for (int kk_ = 0; kk_ < 2; ++kk_)                          \
            acc[QM][QN][i_][j_] = __builtin_amdgcn_mfma_f32_16x16x32_bf16(           \
                AF[i_][kk_], b[j_][kk_], acc[QM][QN][i_][j_], 0, 0, 0);              \
        __builtin_amdgcn_s_setprio(0);                                               \
    } while (0)

#define BAR() __builtin_amdgcn_s_barrier()
#define LGKM0()                                                   \
    do {                                                          \
        asm volatile("s_waitcnt lgkmcnt(0)" ::: "memory");        \
        __builtin_amdgcn_sched_barrier(0);                        \
    } while (0)

__global__ __launch_bounds__(512, 2)
void gemm_persist_kernel(const bf16_t* __restrict__ xb,
                         const bf16_t* __restrict__ w0,
                         const bf16_t* __restrict__ w1,
                         const bf16_t* __restrict__ w2,
                         const float* __restrict__ b0,
                         float* __restrict__ out,
                         int E, int mt, int ntiles) {
    __shared__ bf16_t lds[2][2][2][128][64];  // [buf][op A/B][half][row][k] = 128 KB

    const int tid  = threadIdx.x;
    const int wid  = tid >> 6;
    const int lane = tid & 63;
    const int awr  = wid & 3;    // 32-row block within quadrant
    const int bwc  = wid >> 2;   // 64-col block within quadrant
    const int lrow = lane & 15;
    const int koff = lane >> 4;
    const int sr   = tid >> 3;   // staging row (0..63)
    const int sc   = tid & 7;    // staging 16B chunk
    const int P    = gridDim.x;

    int t = blockIdx.x;
    if (t >= ntiles) return;

    auto make_desc = [&](int tt, TileDesc& d) {
        const int S0 = 4 * mt, S1 = S0 + 6 * mt;
        int mi, ni;
        if (tt < S0) {
            mi = tt >> 2; ni = tt & 3;
            d.A = xb; d.W = w0 + (size_t)ni * 256 * 896;
            d.Y = out + ni * 256; d.bias = b0 + ni * 256;
            d.K = 896; d.NT = 14;
            d.ncol = (896 - ni * 256 < 256) ? (896 - ni * 256) : 256;
        } else if (tt < S1) {
            int l = tt - S0; mi = l / 6; ni = l - mi * 6;
            d.A = xb + 896; d.W = w1 + (size_t)ni * 256 * 1536;
            d.Y = out + 896 + ni * 256; d.bias = nullptr;
            d.K = 1536; d.NT = 24; d.ncol = 256;
        } else {
            int l = tt - S1; mi = l / 5; ni = l - mi * 5;
            d.A = xb + 2432; d.W = w2 + (size_t)ni * 256 * 1280;
            d.Y = out + 2432 + ni * 256; d.bias = nullptr;
            d.K = 1280; d.NT = 20; d.ncol = 256;
        }
        d.m0 = (long)mi * 256;
    };

    auto stage_half = [&](const TileDesc& d, int kt, int bu, int op, int half) {
        #pragma unroll
        for (int s = 0; s < 2; ++s) {
            const int r  = s * 64 + sr;
            const int kc = sc ^ (r & 7);
            const bf16_t* gsrc;
            if (op) {
                gsrc = d.W + (size_t)(half * 128 + r) * d.K + kt * 64 + kc * 8;
            } else {
                long grow = d.m0 + half * 128 + r;
                if (grow >= E) grow = E - 1;  // clamp; outputs row-guarded
                gsrc = d.A + grow * (long)LD + kt * 64 + kc * 8;
            }
            bf16_t* dst = &lds[bu][op][half][0][0] + s * 4096 + wid * 512;
            __builtin_amdgcn_global_load_lds(
                (const __attribute__((address_space(1))) void*)gsrc,
                (__attribute__((address_space(3))) void*)dst, 16, 0, 0);
        }
    };

    bf16x8 a0[2][2], a1[2][2], b[4][2];
    f32x4 acc[2][2][2][4] = {};

    auto load_a = [&](bf16x8 (&a)[2][2], int bu, int half) {
        #pragma unroll
        for (int i = 0; i < 2; ++i)
            #pragma unroll
            for (int kk = 0; kk < 2; ++kk) {
                const int rr = awr * 32 + i * 16 + lrow;
                const int sw = (kk * 4 + koff) ^ (rr & 7);
                a[i][kk] = *(const bf16x8*)(&lds[bu][0][half][rr][sw * 8]);
            }
    };
    auto load_b = [&](int bu, int half) {
        #pragma unroll
        for (int j = 0; j < 4; ++j)
            #pragma unroll
            for (int kk = 0; kk < 2; ++kk) {
                const int rr = bwc * 64 + j * 16 + lrow;
                const int sw = (kk * 4 + koff) ^ (rr & 7);
                b[j][kk] = *(const bf16x8*)(&lds[bu][1][half][rr][sw * 8]);
            }
    };

    auto half_iter = [&](int bu, const TileDesc& sd, int skt, bool dostage) {
        // P1: Q(0,0)
        load_a(a0, bu, 0);
        load_b(bu, 0);
        BAR(); LGKM0();
        MMA_Q(0, 0, a0);
        BAR();
        // P2: Q(1,0); stage A-h0, B-h0 of (sd, skt)
        load_a(a1, bu, 1);
        if (dostage) { stage_half(sd, skt, bu, 0, 0); stage_half(sd, skt, bu, 1, 0); }
        BAR(); LGKM0();
        MMA_Q(1, 0, a1);
        BAR();
        // P3: Q(1,1); stage A-h1
        load_b(bu, 1);
        if (dostage) stage_half(sd, skt, bu, 0, 1);
        BAR(); LGKM0();
        MMA_Q(1, 1, a1);
        BAR();
        // P4: Q(0,1); stage B-h1; counted vmcnt
        if (dostage) {
            stage_half(sd, skt, bu, 1, 1);
            asm volatile("s_waitcnt vmcnt(8)" ::: "memory");
        } else {
            asm volatile("s_waitcnt vmcnt(0)" ::: "memory");
        }
        BAR(); LGKM0();
        MMA_Q(0, 1, a0);
        BAR();
    };

    auto epilogue = [&](const TileDesc& d) {
        #pragma unroll
        for (int qm = 0; qm < 2; ++qm)
            #pragma unroll
            for (int qn = 0; qn < 2; ++qn)
                #pragma unroll
                for (int j = 0; j < 4; ++j) {
                    const int col = qn * 128 + bwc * 64 + j * 16 + lrow;
                    if (col < d.ncol) {
                        const float bv = d.bias ? d.bias[col] : 0.f;
                        #pragma unroll
                        for (int i = 0; i < 2; ++i) {
                            const long rb = d.m0 + qm * 128 + awr * 32 + i * 16 + koff * 4;
                            #pragma unroll
                            for (int r = 0; r < 4; ++r) {
                                const long row = rb + r;
                                if (row < E) d.Y[row * LD + col] = acc[qm][qn][i][j][r] + bv;
                            }
                        }
                    }
                }
    };

    TileDesc cur, nxt;
    make_desc(t, cur);
    int tn = t + P;
    bool has_nxt = tn < ntiles;
    if (has_nxt) make_desc(tn, nxt);

    // prologue: kt0 -> buf0, kt1 -> buf1
    stage_half(cur, 0, 0, 0, 0); stage_half(cur, 0, 0, 0, 1);
    stage_half(cur, 0, 0, 1, 0); stage_half(cur, 0, 0, 1, 1);
    stage_half(cur, 1, 1, 0, 0); stage_half(cur, 1, 1, 0, 1);
    stage_half(cur, 1, 1, 1, 0); stage_half(cur, 1, 1, 1, 1);
    asm volatile("s_waitcnt vmcnt(8)" ::: "memory");
    BAR();

    while (true) {
        const int NITc = cur.NT >> 1;
        #pragma unroll 1
        for (int it = 0; it < NITc - 1; ++it) {
            half_iter(0, cur, 2 * it + 2, true);
            half_iter(1, cur, 2 * it + 3, true);
        }
        // last pair: stage next tile's kt0/kt1 (or drain at the very end)
        if (has_nxt) {
            half_iter(0, nxt, 0, true);
            half_iter(1, nxt, 1, true);
        } else {
            half_iter(0, cur, 0, false);
            half_iter(1, cur, 0, false);
        }

        epilogue(cur);

        if (!has_nxt) break;
        cur = nxt;
        t = tn; tn = t + P;
        has_nxt = tn < ntiles;
        if (has_nxt) make_desc(tn, nxt);

        #pragma unroll
        for (int qm = 0; qm < 2; ++qm)
            #pragma unroll
            for (int qn = 0; qn < 2; ++qn)
                #pragma unroll
                for (int i = 0; i < 2; ++i)
                    #pragma unroll
                    for (int j = 0; j < 4; ++j)
                        acc[qm][qn][i][j] = (f32x4){0.f, 0.f, 0.f, 0.f};
    }
}

// ---------------- fallback 128^2 GEMM (f32 x, reg-staged) ----------------

template <int N, int K, bool BIAS>
__global__ __launch_bounds__(256)
void gemm_fb_kernel(const float* __restrict__ X, const bf16_t* __restrict__ W,
                    const float* __restrict__ bias, float* __restrict__ Y, int M) {
    constexpr int BM = 128, BK = 32;
    constexpr int KT = K / BK;
    __shared__ bf16_t As[BM][BK + 8];
    __shared__ bf16_t Bs[BM][BK];
    const int tid = threadIdx.x, wid = tid >> 6, lane = tid & 63;
    const int wr = wid >> 1, wc = wid & 1;
    const int m0 = blockIdx.y * BM, n0 = blockIdx.x * 128;
    const int srow0 = wid * 16 + (lane >> 2), schunk = lane & 3;
    const int ar = tid >> 3, ac = (tid & 7) * 4;
    const int lrow = lane & 15, koff = lane >> 4;
    f32x4 acc[4][4] = {};
    for (int kt = 0; kt < KT; ++kt) {
        const int k0 = kt * BK;
        #pragma unroll
        for (int s = 0; s < 2; ++s) {
            const int row = srow0 + s * 64;
            const int kc = schunk ^ ((row >> 1) & 3);
            const bf16_t* gsrc = W + (size_t)(n0 + row) * K + k0 + kc * 8;
            bf16_t* ldsbase = &Bs[wid * 16 + s * 64][0];
            __builtin_amdgcn_global_load_lds(
                (const __attribute__((address_space(1))) void*)gsrc,
                (__attribute__((address_space(3))) void*)ldsbase, 16, 0, 0);
        }
        #pragma unroll
        for (int p = 0; p < 4; ++p) {
            const int row = p * 32 + ar;
            const int gr = m0 + row;
            f32x4 v = {};
            if (gr < M) v = *(const f32x4*)(X + (size_t)gr * LD + k0 + ac);
            bf16x4 h;
            h[0] = (bf16_t)v[0]; h[1] = (bf16_t)v[1];
            h[2] = (bf16_t)v[2]; h[3] = (bf16_t)v[3];
            *(bf16x4*)(&As[row][ac]) = h;
        }
        __syncthreads();
        bf16x8 a[4], bb[4];
        #pragma unroll
        for (int i = 0; i < 4; ++i) {
            a[i] = *(const bf16x8*)(&As[wr * 64 + i * 16 + lrow][koff * 8]);
            const int col = wc * 64 + i * 16 + lrow;
            const int kc = koff ^ ((col >> 1) & 3);
            bb[i] = *(const bf16x8*)(&Bs[col][kc * 8]);
        }
        #pragma unroll
        for (int i = 0; i < 4; ++i)
            #pragma unroll
            for (int j = 0; j < 4; ++j)
                acc[i][j] = __builtin_amdgcn_mfma_f32_16x16x32_bf16(a[i], bb[j], acc[i][j], 0, 0, 0);
        __syncthreads();
    }
    #pragma unroll
    for (int j = 0; j < 4; ++j) {
        const int col = n0 + wc * 64 + j * 16 + lrow;
        float bv = 0.f;
        if constexpr (BIAS) bv = bias[col];
        #pragma unroll
        for (int i = 0; i < 4; ++i) {
            const int rbase = m0 + wr * 64 + i * 16 + koff * 4;
            #pragma unroll
            for (int r = 0; r < 4; ++r) {
                const int gr = rbase + r;
                if (gr < M) Y[(size_t)gr * LD + col] = acc[i][j][r] + bv;
            }
        }
    }
}

// ---------------- launch ----------------

extern "C" void kernel_launch(void* const* d_in, const int* in_sizes, int n_in,
                              void* d_out, int out_size, void* d_ws, size_t ws_size,
                              hipStream_t stream) {
    const float* x  = (const float*)d_in[0];
    const float* W0 = (const float*)d_in[1];
    const float* b0 = (const float*)d_in[2];
    const float* W1 = (const float*)d_in[3];
    const float* W2 = (const float*)d_in[4];
    float* out = (float*)d_out;

    const int E = in_sizes[0] / LD;  // 50000

    constexpr size_t W0P = (size_t)1024 * 896;
    constexpr size_t W1S = (size_t)1536 * 1536;
    constexpr size_t W2S = (size_t)1280 * 1280;
    bf16_t* wc0 = (bf16_t*)d_ws;
    bf16_t* wc1 = wc0 + W0P;
    bf16_t* wc2 = wc1 + W1S;
    bf16_t* xb  = wc2 + W2S;

    const size_t need = (W0P + W1S + W2S + (size_t)E * LD) * sizeof(bf16_t);
    const bool fast = ws_size >= need;

    cvt_w0_pad_kernel<<<(int)((W0P + 255) / 256), 256, 0, stream>>>(W0, wc0, 896, 896, (int)W0P);
    combine_wm_kernel<<<(int)(W1S / 256), 256, 0, stream>>>(W1, wc1, 768, 768, (int)W1S);
    combine_wm_kernel<<<(int)(W2S / 256), 256, 0, stream>>>(W2, wc2, 640, 640, (int)W2S);

    if (fast) {
        const long n8 = (long)E * LD / 8;
        cvt_x_kernel<<<4096, 256, 0, stream>>>(x, xb, n8);
        const int mt = (E + 255) / 256;
        const int ntiles = 15 * mt;
        gemm_persist_kernel<<<dim3(256), 512, 0, stream>>>(xb, wc0, wc1, wc2, b0, out, E, mt, ntiles);
    } else {
        const int mt = (E + 127) / 128;
        gemm_fb_kernel<896, 896, true>
            <<<dim3(896 / 128, mt), 256, 0, stream>>>(x, wc0, b0, out, E);
        gemm_fb_kernel<1536, 1536, false>
            <<<dim3(1536 / 128, mt), 256, 0, stream>>>(x + 896, wc1, nullptr, out + 896, E);
        gemm_fb_kernel<1280, 1280, false>
            <<<dim3(1280 / 128, mt), 256, 0, stream>>>(x + 2432, wc2, nullptr, out + 2432, E);
    }
}

// Round 5
// 813.466 us; speedup vs baseline: 1.7662x; 1.7662x over previous
//
#include <hip/hip_runtime.h>
#include <hip/hip_bf16.h>
#include <cstdint>
#include <cstddef>

typedef __bf16 bf16_t;
typedef __bf16 bf16x8 __attribute__((ext_vector_type(8)));
typedef __bf16 bf16x4 __attribute__((ext_vector_type(4)));
typedef float f32x4 __attribute__((ext_vector_type(4)));

static constexpr int LD = 29 * 128;  // 3712 floats per row of x / out

// ---------------- prep kernels ----------------

__global__ void cvt_w0_pad_kernel(const float* __restrict__ in, bf16_t* __restrict__ out,
                                  int rows_real, int kdim, int total) {
    int idx = blockIdx.x * 256 + threadIdx.x;
    if (idx >= total) return;
    int r = idx / kdim;
    int c = idx - r * kdim;
    out[idx] = (bf16_t)((r < rows_real) ? in[(size_t)r * kdim + c] : 0.f);
}

// Wc (2*of x 2*din) from W (2*of x din):
//   rows [0,of):    Wc[j]      = [ W[j,:],    -W[j+of,:] ]
//   rows [of,2of):  Wc[of + j] = [ W[j+of,:],  W[j,:]    ]
__global__ void combine_wm_kernel(const float* __restrict__ W, bf16_t* __restrict__ Wc,
                                  int of, int din, int total) {
    int idx = blockIdx.x * 256 + threadIdx.x;
    if (idx >= total) return;
    int twodin = 2 * din;
    int r = idx / twodin;
    int c = idx - r * twodin;
    float v;
    if (r < of) {
        v = (c < din) ? W[(size_t)r * din + c]
                      : -W[(size_t)(r + of) * din + (c - din)];
    } else {
        int j = r - of;
        v = (c < din) ? W[(size_t)(j + of) * din + c]
                      : W[(size_t)j * din + (c - din)];
    }
    Wc[idx] = (bf16_t)v;
}

__global__ void cvt_x_kernel(const float* __restrict__ in, bf16_t* __restrict__ out, long n8) {
    long stride = (long)gridDim.x * 256;
    for (long i = blockIdx.x * 256L + threadIdx.x; i < n8; i += stride) {
        f32x4 v0 = *(const f32x4*)(in + i * 8);
        f32x4 v1 = *(const f32x4*)(in + i * 8 + 4);
        bf16x8 h;
        h[0] = (bf16_t)v0[0]; h[1] = (bf16_t)v0[1];
        h[2] = (bf16_t)v0[2]; h[3] = (bf16_t)v0[3];
        h[4] = (bf16_t)v1[0]; h[5] = (bf16_t)v1[1];
        h[6] = (bf16_t)v1[2]; h[7] = (bf16_t)v1[3];
        *(bf16x8*)(out + i * 8) = h;
    }
}

// ---------------- 256x256 8-phase GEMM tile body (R3-proven schedule) ----------------
// One tile per block. 512 thr = 8 waves; wave (awr=wid&3, bwc=wid>>2) owns 32x64 of
// each 128x128 quadrant. LDS 2-buf, global_load_lds linear dest, involutive chunk
// swizzle kc = c ^ (row&7) on source & read. vmcnt(8) at phases 4/8, vmcnt(0) only
// in the final K-pair. Stores only in the epilogue (no counted wait after them).

#define MMA_Q(QM, QN, AF)                                                            \
    do {                                                                             \
        __builtin_amdgcn_s_setprio(1);                                               \
        _Pragma("unroll") for (int i_ = 0; i_ < 2; ++i_)                             \
        _Pragma("unroll") for (int j_ = 0; j_ < 4; ++j_)                             \
        _Pragma("unroll") for (int kk_ = 0; kk_ < 2; ++kk_)                          \
            acc[QM][QN][i_][j_] = __builtin_amdgcn_mfma_f32_16x16x32_bf16(           \
                AF[i_][kk_], b[j_][kk_], acc[QM][QN][i_][j_], 0, 0, 0);              \
        __builtin_amdgcn_s_setprio(0);                                               \
    } while (0)

#define BAR() __builtin_amdgcn_s_barrier()
#define LGKM0()                                                   \
    do {                                                          \
        asm volatile("s_waitcnt lgkmcnt(0)" ::: "memory");        \
        __builtin_amdgcn_sched_barrier(0);                        \
    } while (0)

typedef bf16_t lds_t[2][2][2][128][64];  // [buf][op A/B][half][row][k] = 128 KB

template <int K, int NT, bool BIAS>
__device__ __forceinline__ void gemm_tile_body(
        const bf16_t* __restrict__ A,     // segment x base (row stride LD)
        const bf16_t* __restrict__ Wn,    // weight + ni*256*K (row stride K)
        const float* __restrict__ biasn,  // b0 + ni*256 (BIAS only)
        float* __restrict__ Yn,           // out + segoff + ni*256 (row stride LD)
        long m0, int ncol, int E, lds_t& lds) {
    constexpr int NIT = NT / 2;
    static_assert(NT % 2 == 0, "NT even");

    const int tid  = threadIdx.x;
    const int wid  = tid >> 6;
    const int lane = tid & 63;
    const int awr  = wid & 3;
    const int bwc  = wid >> 2;
    const int lrow = lane & 15;
    const int koff = lane >> 4;
    const int sr   = tid >> 3;
    const int sc   = tid & 7;

    auto stage_half = [&](int kt, int bu, int op, int half) {
        #pragma unroll
        for (int s = 0; s < 2; ++s) {
            const int r  = s * 64 + sr;
            const int kc = sc ^ (r & 7);
            const bf16_t* gsrc;
            if (op) {
                gsrc = Wn + (size_t)(half * 128 + r) * K + kt * 64 + kc * 8;
            } else {
                long grow = m0 + half * 128 + r;
                if (grow >= E) grow = E - 1;  // clamp; outputs row-guarded
                gsrc = A + grow * (long)LD + kt * 64 + kc * 8;
            }
            bf16_t* dst = &lds[bu][op][half][0][0] + s * 4096 + wid * 512;
            __builtin_amdgcn_global_load_lds(
                (const __attribute__((address_space(1))) void*)gsrc,
                (__attribute__((address_space(3))) void*)dst, 16, 0, 0);
        }
    };

    bf16x8 a0[2][2], a1[2][2], b[4][2];
    f32x4 acc[2][2][2][4] = {};

    auto load_a = [&](bf16x8 (&a)[2][2], int bu, int half) {
        #pragma unroll
        for (int i = 0; i < 2; ++i)
            #pragma unroll
            for (int kk = 0; kk < 2; ++kk) {
                const int rr = awr * 32 + i * 16 + lrow;
                const int sw = (kk * 4 + koff) ^ (rr & 7);
                a[i][kk] = *(const bf16x8*)(&lds[bu][0][half][rr][sw * 8]);
            }
    };
    auto load_b = [&](int bu, int half) {
        #pragma unroll
        for (int j = 0; j < 4; ++j)
            #pragma unroll
            for (int kk = 0; kk < 2; ++kk) {
                const int rr = bwc * 64 + j * 16 + lrow;
                const int sw = (kk * 4 + koff) ^ (rr & 7);
                b[j][kk] = *(const bf16x8*)(&lds[bu][1][half][rr][sw * 8]);
            }
    };

    auto half_iter = [&](int bu, int skt, bool dostage) {
        // P1: Q(0,0)
        load_a(a0, bu, 0);
        load_b(bu, 0);
        BAR(); LGKM0();
        MMA_Q(0, 0, a0);
        BAR();
        // P2: Q(1,0); stage A-h0, B-h0
        load_a(a1, bu, 1);
        if (dostage) { stage_half(skt, bu, 0, 0); stage_half(skt, bu, 1, 0); }
        BAR(); LGKM0();
        MMA_Q(1, 0, a1);
        BAR();
        // P3: Q(1,1); stage A-h1
        load_b(bu, 1);
        if (dostage) stage_half(skt, bu, 0, 1);
        BAR(); LGKM0();
        MMA_Q(1, 1, a1);
        BAR();
        // P4: Q(0,1); stage B-h1; counted vmcnt
        if (dostage) {
            stage_half(skt, bu, 1, 1);
            asm volatile("s_waitcnt vmcnt(8)" ::: "memory");
        } else {
            asm volatile("s_waitcnt vmcnt(0)" ::: "memory");
        }
        BAR(); LGKM0();
        MMA_Q(0, 1, a0);
        BAR();
    };

    // prologue: kt0 -> buf0, kt1 -> buf1
    stage_half(0, 0, 0, 0); stage_half(0, 0, 0, 1);
    stage_half(0, 0, 1, 0); stage_half(0, 0, 1, 1);
    stage_half(1, 1, 0, 0); stage_half(1, 1, 0, 1);
    stage_half(1, 1, 1, 0); stage_half(1, 1, 1, 1);
    asm volatile("s_waitcnt vmcnt(8)" ::: "memory");
    BAR();

    #pragma unroll 1
    for (int it = 0; it < NIT - 1; ++it) {
        half_iter(0, 2 * it + 2, true);
        half_iter(1, 2 * it + 3, true);
    }
    half_iter(0, 0, false);
    half_iter(1, 0, false);

    // epilogue: C/D layout col = lane&15, row = (lane>>4)*4 + reg
    #pragma unroll
    for (int qm = 0; qm < 2; ++qm)
        #pragma unroll
        for (int qn = 0; qn < 2; ++qn)
            #pragma unroll
            for (int j = 0; j < 4; ++j) {
                const int col = qn * 128 + bwc * 64 + j * 16 + lrow;
                if (col < ncol) {
                    float bv = 0.f;
                    if constexpr (BIAS) bv = biasn[col];
                    #pragma unroll
                    for (int i = 0; i < 2; ++i) {
                        const long rb = m0 + qm * 128 + awr * 32 + i * 16 + koff * 4;
                        #pragma unroll
                        for (int r = 0; r < 4; ++r) {
                            const long row = rb + r;
                            if (row < E) Yn[row * LD + col] = acc[qm][qn][i][j][r] + bv;
                        }
                    }
                }
            }
}

// XCD-colocation remap within a segment (bijective; remainder = identity).
// Blocks b with b%8==x land on XCD x (standard heuristic); map XCD-local slot s
// so that ncol consecutive slots share one mi -> concurrent same-XCD A reuse.
__device__ __forceinline__ int seg_remap(int lb, int ncol, int mt) {
    const int g8   = (mt >> 3) << 3;
    const int full = g8 * ncol;
    if (lb < full) {
        const int x  = lb & 7;
        const int s  = lb >> 3;
        const int s4 = s / ncol;
        const int mem = s - s4 * ncol;
        return (s4 * 8 + x) * ncol + mem;
    }
    return lb;
}

__global__ __launch_bounds__(512, 2)
void gemm_all_kernel(const bf16_t* __restrict__ xb,
                     const bf16_t* __restrict__ w0,
                     const bf16_t* __restrict__ w1,
                     const bf16_t* __restrict__ w2,
                     const float* __restrict__ b0,
                     float* __restrict__ out,
                     int E, int mt) {
    __shared__ lds_t lds;

    const int b  = blockIdx.x;
    const int S0 = 4 * mt;        // seg0 tiles
    const int S1 = S0 + 6 * mt;   // + seg1 tiles

    if (b < S0) {
        const int lt = seg_remap(b, 4, mt);
        const int mi = lt >> 2, ni = lt & 3;
        const int ncol = (ni == 3) ? 128 : 256;  // NREAL = 896
        gemm_tile_body<896, 14, true>(xb, w0 + (size_t)ni * 256 * 896, b0 + ni * 256,
                                      out + ni * 256, (long)mi * 256, ncol, E, lds);
    } else if (b < S1) {
        const int lt = seg_remap(b - S0, 6, mt);
        const int mi = lt / 6, ni = lt - mi * 6;
        gemm_tile_body<1536, 24, false>(xb + 896, w1 + (size_t)ni * 256 * 1536, nullptr,
                                        out + 896 + ni * 256, (long)mi * 256, 256, E, lds);
    } else {
        const int lt = seg_remap(b - S1, 5, mt);
        const int mi = lt / 5, ni = lt - mi * 5;
        gemm_tile_body<1280, 20, false>(xb + 2432, w2 + (size_t)ni * 256 * 1280, nullptr,
                                        out + 2432 + ni * 256, (long)mi * 256, 256, E, lds);
    }
}

// ---------------- fallback 128^2 GEMM (f32 x, reg-staged) ----------------

template <int N, int K, bool BIAS>
__global__ __launch_bounds__(256)
void gemm_fb_kernel(const float* __restrict__ X, const bf16_t* __restrict__ W,
                    const float* __restrict__ bias, float* __restrict__ Y, int M) {
    constexpr int BM = 128, BK = 32;
    constexpr int KT = K / BK;
    __shared__ bf16_t As[BM][BK + 8];
    __shared__ bf16_t Bs[BM][BK];
    const int tid = threadIdx.x, wid = tid >> 6, lane = tid & 63;
    const int wr = wid >> 1, wc = wid & 1;
    const int m0 = blockIdx.y * BM, n0 = blockIdx.x * 128;
    const int srow0 = wid * 16 + (lane >> 2), schunk = lane & 3;
    const int ar = tid >> 3, ac = (tid & 7) * 4;
    const int lrow = lane & 15, koff = lane >> 4;
    f32x4 acc[4][4] = {};
    for (int kt = 0; kt < KT; ++kt) {
        const int k0 = kt * BK;
        #pragma unroll
        for (int s = 0; s < 2; ++s) {
            const int row = srow0 + s * 64;
            const int kc = schunk ^ ((row >> 1) & 3);
            const bf16_t* gsrc = W + (size_t)(n0 + row) * K + k0 + kc * 8;
            bf16_t* ldsbase = &Bs[wid * 16 + s * 64][0];
            __builtin_amdgcn_global_load_lds(
                (const __attribute__((address_space(1))) void*)gsrc,
                (__attribute__((address_space(3))) void*)ldsbase, 16, 0, 0);
        }
        #pragma unroll
        for (int p = 0; p < 4; ++p) {
            const int row = p * 32 + ar;
            const int gr = m0 + row;
            f32x4 v = {};
            if (gr < M) v = *(const f32x4*)(X + (size_t)gr * LD + k0 + ac);
            bf16x4 h;
            h[0] = (bf16_t)v[0]; h[1] = (bf16_t)v[1];
            h[2] = (bf16_t)v[2]; h[3] = (bf16_t)v[3];
            *(bf16x4*)(&As[row][ac]) = h;
        }
        __syncthreads();
        bf16x8 a[4], bb[4];
        #pragma unroll
        for (int i = 0; i < 4; ++i) {
            a[i] = *(const bf16x8*)(&As[wr * 64 + i * 16 + lrow][koff * 8]);
            const int col = wc * 64 + i * 16 + lrow;
            const int kc = koff ^ ((col >> 1) & 3);
            bb[i] = *(const bf16x8*)(&Bs[col][kc * 8]);
        }
        #pragma unroll
        for (int i = 0; i < 4; ++i)
            #pragma unroll
            for (int j = 0; j < 4; ++j)
                acc[i][j] = __builtin_amdgcn_mfma_f32_16x16x32_bf16(a[i], bb[j], acc[i][j], 0, 0, 0);
        __syncthreads();
    }
    #pragma unroll
    for (int j = 0; j < 4; ++j) {
        const int col = n0 + wc * 64 + j * 16 + lrow;
        float bv = 0.f;
        if constexpr (BIAS) bv = bias[col];
        #pragma unroll
        for (int i = 0; i < 4; ++i) {
            const int rbase = m0 + wr * 64 + i * 16 + koff * 4;
            #pragma unroll
            for (int r = 0; r < 4; ++r) {
                const int gr = rbase + r;
                if (gr < M) Y[(size_t)gr * LD + col] = acc[i][j][r] + bv;
            }
        }
    }
}

// ---------------- launch ----------------

extern "C" void kernel_launch(void* const* d_in, const int* in_sizes, int n_in,
                              void* d_out, int out_size, void* d_ws, size_t ws_size,
                              hipStream_t stream) {
    const float* x  = (const float*)d_in[0];
    const float* W0 = (const float*)d_in[1];
    const float* b0 = (const float*)d_in[2];
    const float* W1 = (const float*)d_in[3];
    const float* W2 = (const float*)d_in[4];
    float* out = (float*)d_out;

    const int E = in_sizes[0] / LD;  // 50000

    constexpr size_t W0P = (size_t)1024 * 896;
    constexpr size_t W1S = (size_t)1536 * 1536;
    constexpr size_t W2S = (size_t)1280 * 1280;
    bf16_t* wc0 = (bf16_t*)d_ws;
    bf16_t* wc1 = wc0 + W0P;
    bf16_t* wc2 = wc1 + W1S;
    bf16_t* xb  = wc2 + W2S;

    const size_t need = (W0P + W1S + W2S + (size_t)E * LD) * sizeof(bf16_t);
    const bool fast = ws_size >= need;

    cvt_w0_pad_kernel<<<(int)((W0P + 255) / 256), 256, 0, stream>>>(W0, wc0, 896, 896, (int)W0P);
    combine_wm_kernel<<<(int)(W1S / 256), 256, 0, stream>>>(W1, wc1, 768, 768, (int)W1S);
    combine_wm_kernel<<<(int)(W2S / 256), 256, 0, stream>>>(W2, wc2, 640, 640, (int)W2S);

    if (fast) {
        const long n8 = (long)E * LD / 8;
        cvt_x_kernel<<<4096, 256, 0, stream>>>(x, xb, n8);
        const int mt = (E + 255) / 256;
        gemm_all_kernel<<<dim3(15 * mt), 512, 0, stream>>>(xb, wc0, wc1, wc2, b0, out, E, mt);
    } else {
        const int mt = (E + 127) / 128;
        gemm_fb_kernel<896, 896, true>
            <<<dim3(896 / 128, mt), 256, 0, stream>>>(x, wc0, b0, out, E);
        gemm_fb_kernel<1536, 1536, false>
            <<<dim3(1536 / 128, mt), 256, 0, stream>>>(x + 896, wc1, nullptr, out + 896, E);
        gemm_fb_kernel<1280, 1280, false>
            <<<dim3(1280 / 128, mt), 256, 0, stream>>>(x + 2432, wc2, nullptr, out + 2432, E);
    }
}

// Round 6
// 796.975 us; speedup vs baseline: 1.8027x; 1.0207x over previous
//
#include <hip/hip_runtime.h>
#include <hip/hip_bf16.h>
#include <cstdint>
#include <cstddef>

typedef __bf16 bf16_t;
typedef __bf16 bf16x8 __attribute__((ext_vector_type(8)));
typedef __bf16 bf16x4 __attribute__((ext_vector_type(4)));
typedef float f32x4 __attribute__((ext_vector_type(4)));

static constexpr int LD = 29 * 128;  // 3712 floats per row of x / out

template <int N> struct IC { static constexpr int v = N; };

// ---------------- prep kernels ----------------

__global__ void cvt_w0_pad_kernel(const float* __restrict__ in, bf16_t* __restrict__ out,
                                  int rows_real, int kdim, int total) {
    int idx = blockIdx.x * 256 + threadIdx.x;
    if (idx >= total) return;
    int r = idx / kdim;
    int c = idx - r * kdim;
    out[idx] = (bf16_t)((r < rows_real) ? in[(size_t)r * kdim + c] : 0.f);
}

// Wc (2*of x 2*din) from W (2*of x din):
//   rows [0,of):    Wc[j]      = [ W[j,:],    -W[j+of,:] ]
//   rows [of,2of):  Wc[of + j] = [ W[j+of,:],  W[j,:]    ]
__global__ void combine_wm_kernel(const float* __restrict__ W, bf16_t* __restrict__ Wc,
                                  int of, int din, int total) {
    int idx = blockIdx.x * 256 + threadIdx.x;
    if (idx >= total) return;
    int twodin = 2 * din;
    int r = idx / twodin;
    int c = idx - r * twodin;
    float v;
    if (r < of) {
        v = (c < din) ? W[(size_t)r * din + c]
                      : -W[(size_t)(r + of) * din + (c - din)];
    } else {
        int j = r - of;
        v = (c < din) ? W[(size_t)(j + of) * din + c]
                      : W[(size_t)j * din + (c - din)];
    }
    Wc[idx] = (bf16_t)v;
}

__global__ void cvt_x_kernel(const float* __restrict__ in, bf16_t* __restrict__ out, long n8) {
    long stride = (long)gridDim.x * 256;
    for (long i = blockIdx.x * 256L + threadIdx.x; i < n8; i += stride) {
        f32x4 v0 = *(const f32x4*)(in + i * 8);
        f32x4 v1 = *(const f32x4*)(in + i * 8 + 4);
        bf16x8 h;
        h[0] = (bf16_t)v0[0]; h[1] = (bf16_t)v0[1];
        h[2] = (bf16_t)v0[2]; h[3] = (bf16_t)v0[3];
        h[4] = (bf16_t)v1[0]; h[5] = (bf16_t)v1[1];
        h[6] = (bf16_t)v1[2]; h[7] = (bf16_t)v1[3];
        *(bf16x8*)(out + i * 8) = h;
    }
}

// ---------------- 256x256 8-phase GEMM tile body ----------------
// R3-proven schedule, compile-time addressing: bu/op/half are template-constant,
// ds_read byte offsets and global source base pointers precomputed per tile.
// vmcnt(8) at phases 4/8; vmcnt(0) only in the final K-pair; stores only in epilogue.

#define MMA_Q(QM, QN, AF)                                                            \
    do {                                                                             \
        __builtin_amdgcn_s_setprio(1);                                               \
        _Pragma("unroll") for (int i_ = 0; i_ < 2; ++i_)                             \
        _Pragma("unroll") for (int j_ = 0; j_ < 4; ++j_)                             \
        _Pragma("unroll") for (int kk_ = 0; kk_ < 2; ++kk_)                          \
            acc[QM][QN][i_][j_] = __builtin_amdgcn_mfma_f32_16x16x32_bf16(           \
                AF[i_][kk_], b[j_][kk_], acc[QM][QN][i_][j_], 0, 0, 0);              \
        __builtin_amdgcn_s_setprio(0);                                               \
    } while (0)

#define BAR() __builtin_amdgcn_s_barrier()
#define LGKM0()                                                   \
    do {                                                          \
        asm volatile("s_waitcnt lgkmcnt(0)" ::: "memory");        \
        __builtin_amdgcn_sched_barrier(0);                        \
    } while (0)

typedef bf16_t lds_t[2][2][2][128][64];  // [buf][op A/B][half][row][k] = 128 KB

template <int K, int NT, bool BIAS>
__device__ __forceinline__ void gemm_tile_body(
        const bf16_t* __restrict__ A,     // segment x base (row stride LD)
        const bf16_t* __restrict__ Wn,    // weight + ni*256*K (row stride K)
        const float* __restrict__ biasn,  // b0 + ni*256 (BIAS only)
        float* __restrict__ Yn,           // out + segoff + ni*256 (row stride LD)
        long m0, int ncol, int E, lds_t& lds) {
    constexpr int NIT = NT / 2;
    static_assert(NT % 2 == 0, "NT even");

    const int tid  = threadIdx.x;
    const int wid  = tid >> 6;
    const int lane = tid & 63;
    const int awr  = wid & 3;
    const int bwc  = wid >> 2;
    const int lrow = lane & 15;
    const int koff = lane >> 4;
    const int sr   = tid >> 3;
    const int sc   = tid & 7;

    // ---- precomputed thread-constant ds_read byte offsets (within one half-block)
    int offA[2][2], offB[4][2];
    #pragma unroll
    for (int i = 0; i < 2; ++i)
        #pragma unroll
        for (int kk = 0; kk < 2; ++kk) {
            const int rr = awr * 32 + i * 16 + lrow;
            offA[i][kk] = rr * 128 + (((kk * 4 + koff) ^ (rr & 7)) * 16);
        }
    #pragma unroll
    for (int j = 0; j < 4; ++j)
        #pragma unroll
        for (int kk = 0; kk < 2; ++kk) {
            const int rr = bwc * 64 + j * 16 + lrow;
            offB[j][kk] = rr * 128 + (((kk * 4 + koff) ^ (rr & 7)) * 16);
        }

    // ---- precomputed gl_lds source base pointers (kt = 0)
    const bf16_t* gA[2][2];
    const bf16_t* gB[2][2];
    #pragma unroll
    for (int hf = 0; hf < 2; ++hf)
        #pragma unroll
        for (int s = 0; s < 2; ++s) {
            const int r  = s * 64 + sr;
            const int kc = sc ^ (r & 7);
            long grow = m0 + hf * 128 + r;
            if (grow >= E) grow = E - 1;  // clamp; outputs row-guarded
            gA[hf][s] = A + grow * (long)LD + kc * 8;
            gB[hf][s] = Wn + (size_t)(hf * 128 + r) * K + kc * 8;
        }
    const int dstw = wid * 1024;  // wave's byte chunk within an [s] sub-block

    bf16x8 a0[2][2], a1[2][2], b[4][2];
    f32x4 acc[2][2][2][4] = {};

    auto stage = [&](auto BUc, auto OPc, auto HFc, int kt) {
        constexpr int BU = decltype(BUc)::v;
        constexpr int OP = decltype(OPc)::v;
        constexpr int HF = decltype(HFc)::v;
        const long kof = (long)kt * 64;
        #pragma unroll
        for (int s = 0; s < 2; ++s) {
            const bf16_t* gsrc = (OP ? gB[HF][s] : gA[HF][s]) + kof;
            char* dst = (char*)&lds[BU][OP][HF][0][0] + s * 8192 + dstw;
            __builtin_amdgcn_global_load_lds(
                (const __attribute__((address_space(1))) void*)gsrc,
                (__attribute__((address_space(3))) void*)dst, 16, 0, 0);
        }
    };

    auto load_a = [&](bf16x8 (&a)[2][2], auto BUc, auto HFc) {
        constexpr int BU = decltype(BUc)::v;
        constexpr int HF = decltype(HFc)::v;
        const char* base = (const char*)&lds[BU][0][HF][0][0];
        #pragma unroll
        for (int i = 0; i < 2; ++i)
            #pragma unroll
            for (int kk = 0; kk < 2; ++kk)
                a[i][kk] = *(const bf16x8*)(base + offA[i][kk]);
    };
    auto load_b = [&](auto BUc, auto HFc) {
        constexpr int BU = decltype(BUc)::v;
        constexpr int HF = decltype(HFc)::v;
        const char* base = (const char*)&lds[BU][1][HF][0][0];
        #pragma unroll
        for (int j = 0; j < 4; ++j)
            #pragma unroll
            for (int kk = 0; kk < 2; ++kk)
                b[j][kk] = *(const bf16x8*)(base + offB[j][kk]);
    };

    auto half_iter = [&](auto BUc, auto STc, int skt) {
        constexpr int ST = decltype(STc)::v;
        // P1: Q(0,0)
        load_a(a0, BUc, IC<0>{});
        load_b(BUc, IC<0>{});
        BAR(); LGKM0();
        MMA_Q(0, 0, a0);
        BAR();
        // P2: Q(1,0); stage A-h0, B-h0
        load_a(a1, BUc, IC<1>{});
        if constexpr (ST) { stage(BUc, IC<0>{}, IC<0>{}, skt); stage(BUc, IC<1>{}, IC<0>{}, skt); }
        BAR(); LGKM0();
        MMA_Q(1, 0, a1);
        BAR();
        // P3: Q(1,1); stage A-h1
        load_b(BUc, IC<1>{});
        if constexpr (ST) stage(BUc, IC<0>{}, IC<1>{}, skt);
        BAR(); LGKM0();
        MMA_Q(1, 1, a1);
        BAR();
        // P4: Q(0,1); stage B-h1; counted vmcnt
        if constexpr (ST) {
            stage(BUc, IC<1>{}, IC<1>{}, skt);
            asm volatile("s_waitcnt vmcnt(8)" ::: "memory");
        } else {
            asm volatile("s_waitcnt vmcnt(0)" ::: "memory");
        }
        BAR(); LGKM0();
        MMA_Q(0, 1, a0);
        BAR();
    };

    // prologue: kt0 -> buf0, kt1 -> buf1
    stage(IC<0>{}, IC<0>{}, IC<0>{}, 0); stage(IC<0>{}, IC<0>{}, IC<1>{}, 0);
    stage(IC<0>{}, IC<1>{}, IC<0>{}, 0); stage(IC<0>{}, IC<1>{}, IC<1>{}, 0);
    stage(IC<1>{}, IC<0>{}, IC<0>{}, 1); stage(IC<1>{}, IC<0>{}, IC<1>{}, 1);
    stage(IC<1>{}, IC<1>{}, IC<0>{}, 1); stage(IC<1>{}, IC<1>{}, IC<1>{}, 1);
    asm volatile("s_waitcnt vmcnt(8)" ::: "memory");
    BAR();

    #pragma unroll 1
    for (int it = 0; it < NIT - 1; ++it) {
        half_iter(IC<0>{}, IC<1>{}, 2 * it + 2);
        half_iter(IC<1>{}, IC<1>{}, 2 * it + 3);
    }
    half_iter(IC<0>{}, IC<0>{}, 0);
    half_iter(IC<1>{}, IC<0>{}, 0);

    // epilogue: C/D layout col = lane&15, row = (lane>>4)*4 + reg
    #pragma unroll
    for (int qm = 0; qm < 2; ++qm)
        #pragma unroll
        for (int qn = 0; qn < 2; ++qn)
            #pragma unroll
            for (int j = 0; j < 4; ++j) {
                const int col = qn * 128 + bwc * 64 + j * 16 + lrow;
                if (col < ncol) {
                    float bv = 0.f;
                    if constexpr (BIAS) bv = biasn[col];
                    #pragma unroll
                    for (int i = 0; i < 2; ++i) {
                        const long rb = m0 + qm * 128 + awr * 32 + i * 16 + koff * 4;
                        #pragma unroll
                        for (int r = 0; r < 4; ++r) {
                            const long row = rb + r;
                            if (row < E) Yn[row * LD + col] = acc[qm][qn][i][j][r] + bv;
                        }
                    }
                }
            }
}

// XCD-colocation remap within a segment (bijective; remainder = identity).
__device__ __forceinline__ int seg_remap(int lb, int ncol, int mt) {
    const int g8   = (mt >> 3) << 3;
    const int full = g8 * ncol;
    if (lb < full) {
        const int x  = lb & 7;
        const int s  = lb >> 3;
        const int s4 = s / ncol;
        const int mem = s - s4 * ncol;
        return (s4 * 8 + x) * ncol + mem;
    }
    return lb;
}

__global__ __launch_bounds__(512, 2)
void gemm_all_kernel(const bf16_t* __restrict__ xb,
                     const bf16_t* __restrict__ w0,
                     const bf16_t* __restrict__ w1,
                     const bf16_t* __restrict__ w2,
                     const float* __restrict__ b0,
                     float* __restrict__ out,
                     int E, int mt) {
    __shared__ lds_t lds;

    const int b  = blockIdx.x;
    const int S0 = 4 * mt;
    const int S1 = S0 + 6 * mt;

    if (b < S0) {
        const int lt = seg_remap(b, 4, mt);
        const int mi = lt >> 2, ni = lt & 3;
        const int ncol = (ni == 3) ? 128 : 256;  // NREAL = 896
        gemm_tile_body<896, 14, true>(xb, w0 + (size_t)ni * 256 * 896, b0 + ni * 256,
                                      out + ni * 256, (long)mi * 256, ncol, E, lds);
    } else if (b < S1) {
        const int lt = seg_remap(b - S0, 6, mt);
        const int mi = lt / 6, ni = lt - mi * 6;
        gemm_tile_body<1536, 24, false>(xb + 896, w1 + (size_t)ni * 256 * 1536, nullptr,
                                        out + 896 + ni * 256, (long)mi * 256, 256, E, lds);
    } else {
        const int lt = seg_remap(b - S1, 5, mt);
        const int mi = lt / 5, ni = lt - mi * 5;
        gemm_tile_body<1280, 20, false>(xb + 2432, w2 + (size_t)ni * 256 * 1280, nullptr,
                                        out + 2432 + ni * 256, (long)mi * 256, 256, E, lds);
    }
}

// ---------------- fallback 128^2 GEMM (f32 x, reg-staged) ----------------

template <int N, int K, bool BIAS>
__global__ __launch_bounds__(256)
void gemm_fb_kernel(const float* __restrict__ X, const bf16_t* __restrict__ W,
                    const float* __restrict__ bias, float* __restrict__ Y, int M) {
    constexpr int BM = 128, BK = 32;
    constexpr int KT = K / BK;
    __shared__ bf16_t As[BM][BK + 8];
    __shared__ bf16_t Bs[BM][BK];
    const int tid = threadIdx.x, wid = tid >> 6, lane = tid & 63;
    const int wr = wid >> 1, wc = wid & 1;
    const int m0 = blockIdx.y * BM, n0 = blockIdx.x * 128;
    const int srow0 = wid * 16 + (lane >> 2), schunk = lane & 3;
    const int ar = tid >> 3, ac = (tid & 7) * 4;
    const int lrow = lane & 15, koff = lane >> 4;
    f32x4 acc[4][4] = {};
    for (int kt = 0; kt < KT; ++kt) {
        const int k0 = kt * BK;
        #pragma unroll
        for (int s = 0; s < 2; ++s) {
            const int row = srow0 + s * 64;
            const int kc = schunk ^ ((row >> 1) & 3);
            const bf16_t* gsrc = W + (size_t)(n0 + row) * K + k0 + kc * 8;
            bf16_t* ldsbase = &Bs[wid * 16 + s * 64][0];
            __builtin_amdgcn_global_load_lds(
                (const __attribute__((address_space(1))) void*)gsrc,
                (__attribute__((address_space(3))) void*)ldsbase, 16, 0, 0);
        }
        #pragma unroll
        for (int p = 0; p < 4; ++p) {
            const int row = p * 32 + ar;
            const int gr = m0 + row;
            f32x4 v = {};
            if (gr < M) v = *(const f32x4*)(X + (size_t)gr * LD + k0 + ac);
            bf16x4 h;
            h[0] = (bf16_t)v[0]; h[1] = (bf16_t)v[1];
            h[2] = (bf16_t)v[2]; h[3] = (bf16_t)v[3];
            *(bf16x4*)(&As[row][ac]) = h;
        }
        __syncthreads();
        bf16x8 a[4], bb[4];
        #pragma unroll
        for (int i = 0; i < 4; ++i) {
            a[i] = *(const bf16x8*)(&As[wr * 64 + i * 16 + lrow][koff * 8]);
            const int col = wc * 64 + i * 16 + lrow;
            const int kc = koff ^ ((col >> 1) & 3);
            bb[i] = *(const bf16x8*)(&Bs[col][kc * 8]);
        }
        #pragma unroll
        for (int i = 0; i < 4; ++i)
            #pragma unroll
            for (int j = 0; j < 4; ++j)
                acc[i][j] = __builtin_amdgcn_mfma_f32_16x16x32_bf16(a[i], bb[j], acc[i][j], 0, 0, 0);
        __syncthreads();
    }
    #pragma unroll
    for (int j = 0; j < 4; ++j) {
        const int col = n0 + wc * 64 + j * 16 + lrow;
        float bv = 0.f;
        if constexpr (BIAS) bv = bias[col];
        #pragma unroll
        for (int i = 0; i < 4; ++i) {
            const int rbase = m0 + wr * 64 + i * 16 + koff * 4;
            #pragma unroll
            for (int r = 0; r < 4; ++r) {
                const int gr = rbase + r;
                if (gr < M) Y[(size_t)gr * LD + col] = acc[i][j][r] + bv;
            }
        }
    }
}

// ---------------- launch ----------------

extern "C" void kernel_launch(void* const* d_in, const int* in_sizes, int n_in,
                              void* d_out, int out_size, void* d_ws, size_t ws_size,
                              hipStream_t stream) {
    const float* x  = (const float*)d_in[0];
    const float* W0 = (const float*)d_in[1];
    const float* b0 = (const float*)d_in[2];
    const float* W1 = (const float*)d_in[3];
    const float* W2 = (const float*)d_in[4];
    float* out = (float*)d_out;

    const int E = in_sizes[0] / LD;  // 50000

    constexpr size_t W0P = (size_t)1024 * 896;
    constexpr size_t W1S = (size_t)1536 * 1536;
    constexpr size_t W2S = (size_t)1280 * 1280;
    bf16_t* wc0 = (bf16_t*)d_ws;
    bf16_t* wc1 = wc0 + W0P;
    bf16_t* wc2 = wc1 + W1S;
    bf16_t* xb  = wc2 + W2S;

    const size_t need = (W0P + W1S + W2S + (size_t)E * LD) * sizeof(bf16_t);
    const bool fast = ws_size >= need;

    cvt_w0_pad_kernel<<<(int)((W0P + 255) / 256), 256, 0, stream>>>(W0, wc0, 896, 896, (int)W0P);
    combine_wm_kernel<<<(int)(W1S / 256), 256, 0, stream>>>(W1, wc1, 768, 768, (int)W1S);
    combine_wm_kernel<<<(int)(W2S / 256), 256, 0, stream>>>(W2, wc2, 640, 640, (int)W2S);

    if (fast) {
        const long n8 = (long)E * LD / 8;
        cvt_x_kernel<<<4096, 256, 0, stream>>>(x, xb, n8);
        const int mt = (E + 255) / 256;
        gemm_all_kernel<<<dim3(15 * mt), 512, 0, stream>>>(xb, wc0, wc1, wc2, b0, out, E, mt);
    } else {
        const int mt = (E + 127) / 128;
        gemm_fb_kernel<896, 896, true>
            <<<dim3(896 / 128, mt), 256, 0, stream>>>(x, wc0, b0, out, E);
        gemm_fb_kernel<1536, 1536, false>
            <<<dim3(1536 / 128, mt), 256, 0, stream>>>(x + 896, wc1, nullptr, out + 896, E);
        gemm_fb_kernel<1280, 1280, false>
            <<<dim3(1280 / 128, mt), 256, 0, stream>>>(x + 2432, wc2, nullptr, out + 2432, E);
    }
}